// Round 5
// baseline (374.394 us; speedup 1.0000x reference)
//
#include <hip/hip_runtime.h>
#include <math.h>

typedef unsigned int uint32;
typedef unsigned short u16;

#if __has_builtin(__builtin_amdgcn_exp2f)
#define EXP2F(x) __builtin_amdgcn_exp2f(x)
#else
#define EXP2F(x) exp2f(x)
#endif

__device__ __forceinline__ u16 f2bf(float f) {  // RNE
    uint32 u = __float_as_uint(f);
    u += 0x7fffu + ((u >> 16) & 1u);
    return (u16)(u >> 16);
}
__device__ __forceinline__ float bflo(uint32 v) { return __uint_as_float(v << 16); }
__device__ __forceinline__ float bfhi(uint32 v) { return __uint_as_float(v & 0xffff0000u); }

// ---- fused: [0,LB) linear+gate blocks; [LB,..) count blocks ------------------
#define LROWS 16
__global__ __launch_bounds__(256) void fused_pre(
    const float* __restrict__ x, const float* __restrict__ wl, const float* __restrict__ bl,
    const float* __restrict__ wr, const float* __restrict__ br,
    const float* __restrict__ gw, const float* __restrict__ gb,
    u16* __restrict__ xl, float* __restrict__ xr, float* __restrict__ gate4,
    const int* __restrict__ e0, const int* __restrict__ e1, const int* __restrict__ e2,
    int* __restrict__ counts, u16* __restrict__ rank,
    int N, int E, int T, int LB)
{
    if ((int)blockIdx.x >= LB) {
        int t = ((int)blockIdx.x - LB) * 256 + (int)threadIdx.x;
        if (t < T) {
            int hop, dst;
            if (t < E)          { hop = 0; dst = e0[E + t]; }
            else if (t < 2 * E) { hop = 1; dst = e1[t]; }
            else if (t < 3 * E) { hop = 2; dst = e2[t - E]; }
            else                { hop = 0; dst = t - 3 * E; }
            rank[t] = (u16)atomicAdd(counts + (size_t)hop * N + dst, 1);
        }
        return;
    }
    __shared__ float4 sx[LROWS][32];
    __shared__ float gbuf[LROWS][3];
    int t = threadIdx.x;
    int r0 = blockIdx.x * LROWS;
    int nr = min(LROWS, N - r0);
    {
        const float4* xi = (const float4*)(x + (size_t)r0 * 128);
        for (int i = t; i < nr * 32; i += 256) ((float4*)sx)[i] = xi[i];
    }
    __syncthreads();
    int mat = t >> 7, col = t & 127;
    const float* w = mat ? wr : wl;
    float acc[LROWS];
#pragma unroll
    for (int r = 0; r < LROWS; ++r) acc[r] = 0.f;
    for (int i = 0; i < 128; i += 4) {
        float w0 = w[(i + 0) * 128 + col];
        float w1 = w[(i + 1) * 128 + col];
        float w2 = w[(i + 2) * 128 + col];
        float w3 = w[(i + 3) * 128 + col];
#pragma unroll
        for (int r = 0; r < LROWS; ++r) {
            float4 xv = sx[r][i >> 2];
            acc[r] = fmaf(xv.x, w0, acc[r]);
            acc[r] = fmaf(xv.y, w1, acc[r]);
            acc[r] = fmaf(xv.z, w2, acc[r]);
            acc[r] = fmaf(xv.w, w3, acc[r]);
        }
    }
    if (mat) {
        float b = br[col];
        for (int r = 0; r < nr; ++r) xr[(size_t)(r0 + r) * 128 + col] = acc[r] + b;
    } else {
        float b = bl[col];
        for (int r = 0; r < nr; ++r) xl[(size_t)(r0 + r) * 128 + col] = f2bf(acc[r] + b);
    }
    if (t < nr * 3) {
        int r = t / 3, k = t - 3 * r;
        float s = 0.f;
        const float4* xrow = sx[r];
#pragma unroll 4
        for (int i = 0; i < 32; ++i) {
            float4 v = xrow[i];
            s += v.x * gw[(4 * i + 0) * 3 + k] + v.y * gw[(4 * i + 1) * 3 + k]
               + v.z * gw[(4 * i + 2) * 3 + k] + v.w * gw[(4 * i + 3) * 3 + k];
        }
        gbuf[r][k] = s + gb[k];
    }
    __syncthreads();
    if (t < nr) {
        float s0 = gbuf[t][0], s1 = gbuf[t][1], s2 = gbuf[t][2];
        float mx = fmaxf(s0, fmaxf(s1, s2));
        float e0v = __expf(s0 - mx), e1v = __expf(s1 - mx), e2v = __expf(s2 - mx);
        float inv = 1.f / (e0v + e1v + e2v);
        *(float4*)(gate4 + (size_t)(r0 + t) * 4) = make_float4(e0v * inv, e1v * inv, e2v * inv, 0.f);
    }
}

// ---- scans (block prefix folded at read time) --------------------------------
__global__ __launch_bounds__(1024) void scan1(const int* __restrict__ counts, int M,
                                              int* __restrict__ offsets, int* __restrict__ partials) {
    __shared__ int s[1024];
    int t = threadIdx.x;
    int i = blockIdx.x * 1024 + t;
    int v = (i < M) ? counts[i] : 0;
    s[t] = v;
    __syncthreads();
    for (int o = 1; o < 1024; o <<= 1) {
        int u = (t >= o) ? s[t - o] : 0;
        __syncthreads();
        s[t] += u;
        __syncthreads();
    }
    if (i < M) offsets[i] = s[t] - v;
    if (t == 1023) partials[blockIdx.x] = s[1023];
}

__global__ __launch_bounds__(1024) void scan2(int* __restrict__ partials, int G) {
    __shared__ int s[1024];
    int t = threadIdx.x;
    int v = (t < G) ? partials[t] : 0;
    s[t] = v;
    __syncthreads();
    for (int o = 1; o < 1024; o <<= 1) {
        int u = (t >= o) ? s[t - o] : 0;
        __syncthreads();
        s[t] += u;
        __syncthreads();
    }
    if (t < G) partials[t] = s[t] - v;
}

__global__ void scatter_all(const int* __restrict__ e0, const int* __restrict__ e1,
                            const int* __restrict__ e2, int E, int N,
                            const int* __restrict__ offsets, const int* __restrict__ partials,
                            const u16* __restrict__ rank, u16* __restrict__ csr_src, int T) {
    int t = blockIdx.x * blockDim.x + threadIdx.x;
    if (t >= T) return;
    if (t < 8) csr_src[T + t] = 0;  // pad for node_all's unconditional prefetch
    int hop, src, dst;
    if (t < E)          { hop = 0; src = e0[t];         dst = e0[E + t]; }
    else if (t < 2 * E) { hop = 1; src = e1[t - E];     dst = e1[t]; }
    else if (t < 3 * E) { hop = 2; src = e2[t - 2 * E]; dst = e2[t - E]; }
    else                { hop = 0; src = t - 3 * E;     dst = src; }
    int i = hop * N + dst;
    int p = offsets[i] + partials[i >> 10] + (int)rank[t];
    csr_src[p] = (u16)src;
}

// ---- node kernel: wave per node, 2 edges/iter, 32 lanes/edge, no-max softmax --
// half = lane>>5 (edge slot), l5 = lane&31 covers features 4*l5..+3; head = l5>>3.
__global__ __launch_bounds__(256) void node_all(
    const uint2* __restrict__ xlv,   // [N*32], uint2 = 4 bf16
    const float* __restrict__ xr,    // [N*128]
    const u16* __restrict__ csr,
    const int* __restrict__ offsets, const int* __restrict__ partials,
    const float* __restrict__ att,   // [3*128]
    const float* __restrict__ bias,  // [3*32]
    const float* __restrict__ gate4, // [N*4]
    float* __restrict__ out,         // [N*32]
    int N, int M, int T)
{
    const float L2E = 1.44269504088896f;
    int wid = (int)((blockIdx.x * (size_t)blockDim.x + threadIdx.x) >> 6);
    int lane = threadIdx.x & 63;
    if (wid >= N) return;
    int n = wid;
    int half = lane >> 5, l5 = lane & 31;

    float4 r4 = ((const float4*)(xr + (size_t)n * 128))[l5];
    float4 gv = ((const float4*)gate4)[n];
    float res0 = 0.f, res1 = 0.f, res2 = 0.f, res3 = 0.f;

#pragma unroll
    for (int h = 0; h < 3; ++h) {
        float4 a4 = ((const float4*)(att + h * 128))[l5];
        a4.x *= L2E; a4.y *= L2E; a4.z *= L2E; a4.w *= L2E;
        int i = h * N + n;
        int beg = offsets[i] + partials[i >> 10];
        int i1 = i + 1;
        int end = (i1 == M) ? T : (offsets[i1] + partials[i1 >> 10]);
        float d = 0.f, acc0 = 0.f, acc1 = 0.f, acc2 = 0.f, acc3 = 0.f;
        if (beg < end) {
            int sc = csr[beg + half];          // row for iter 0
            int sn = csr[beg + 2 + half];      // row for iter 1
            uint2 lv = xlv[(size_t)sc * 32 + l5];
            for (int e = beg; e < end; e += 2) {
                uint2 cv = lv;
                bool valid = (e + half) < end;
                int sf = csr[e + 4 + half];            // csr prefetch, 2 iters ahead (pad-safe)
                lv = xlv[(size_t)sn * 32 + l5];        // row prefetch, 1 iter ahead
                sn = sf;
                float lx0 = bflo(cv.x), lx1 = bfhi(cv.x);
                float lx2 = bflo(cv.y), lx3 = bfhi(cv.y);
                float g0 = lx0 + r4.x, g1 = lx1 + r4.y;
                float g2 = lx2 + r4.z, g3 = lx3 + r4.w;
                float p;                                // leaky = 0.6g + 0.4|g|
                p = fmaf(0.4f, fabsf(g0), 0.6f * g0) * a4.x;
                p = fmaf(fmaf(0.4f, fabsf(g1), 0.6f * g1), a4.y, p);
                p = fmaf(fmaf(0.4f, fabsf(g2), 0.6f * g2), a4.z, p);
                p = fmaf(fmaf(0.4f, fabsf(g3), 0.6f * g3), a4.w, p);
                p += __shfl_xor(p, 1);
                p += __shfl_xor(p, 2);
                p += __shfl_xor(p, 4);                  // head logit * log2e
                float wv = EXP2F(p);
                wv = valid ? wv : 0.f;
                d += wv;
                acc0 = fmaf(wv, lx0, acc0);
                acc1 = fmaf(wv, lx1, acc1);
                acc2 = fmaf(wv, lx2, acc2);
                acc3 = fmaf(wv, lx3, acc3);
            }
        }
        // combine edge halves (lane bit 5)
        d += __shfl_xor(d, 32);
        acc0 += __shfl_xor(acc0, 32);
        acc1 += __shfl_xor(acc1, 32);
        acc2 += __shfl_xor(acc2, 32);
        acc3 += __shfl_xor(acc3, 32);
        float inv = (d > 0.f) ? (1.0f / d) : 0.f;  // deg==0 -> msg = bias
        float q0 = acc0 * inv, q1 = acc1 * inv, q2 = acc2 * inv, q3 = acc3 * inv;
        // sum over 4 heads (lane bits 3,4)
        q0 += __shfl_xor(q0, 8);  q0 += __shfl_xor(q0, 16);
        q1 += __shfl_xor(q1, 8);  q1 += __shfl_xor(q1, 16);
        q2 += __shfl_xor(q2, 8);  q2 += __shfl_xor(q2, 16);
        q3 += __shfl_xor(q3, 8);  q3 += __shfl_xor(q3, 16);
        float4 b4 = ((const float4*)(bias + h * 32))[l5 & 7];
        float g = (h == 0) ? gv.x : ((h == 1) ? gv.y : gv.z);
        res0 = fmaf(g, fmaf(q0, 0.25f, b4.x), res0);
        res1 = fmaf(g, fmaf(q1, 0.25f, b4.y), res1);
        res2 = fmaf(g, fmaf(q2, 0.25f, b4.z), res2);
        res3 = fmaf(g, fmaf(q3, 0.25f, b4.w), res3);
    }
    if (lane < 8) ((float4*)(out + (size_t)n * 32))[lane] = make_float4(res0, res1, res2, res3);
}

// ---------------- launch ----------------
extern "C" void kernel_launch(void* const* d_in, const int* in_sizes, int n_in,
                              void* d_out, int out_size, void* d_ws, size_t ws_size,
                              hipStream_t stream) {
    const float* x  = (const float*)d_in[0];
    const int* e0 = (const int*)d_in[1];
    const int* e1 = (const int*)d_in[2];
    const int* e2 = (const int*)d_in[3];
    const float* wl = (const float*)d_in[4];
    const float* bl = (const float*)d_in[5];
    const float* wr = (const float*)d_in[6];
    const float* br = (const float*)d_in[7];
    const float* att = (const float*)d_in[8];
    const float* cb  = (const float*)d_in[9];
    const float* gw  = (const float*)d_in[10];
    const float* gb  = (const float*)d_in[11];

    int N = in_sizes[0] / 128;
    int E = in_sizes[1] / 2;
    float* out = (float*)d_out;

    char* ws = (char*)d_ws;
    u16* xl      = (u16*)ws;   ws += (size_t)N * 128 * 2;
    float* xr    = (float*)ws; ws += (size_t)N * 128 * 4;
    float* gate4 = (float*)ws; ws += (size_t)N * 4 * 4;
    int M = 3 * N;
    int T = 3 * E + N;
    int* offsets  = (int*)ws; ws += (size_t)M * 4;
    int* counts   = (int*)ws; ws += (size_t)M * 4;
    int* partials = (int*)ws; ws += 4096;
    u16* rank     = (u16*)ws; ws += (size_t)T * 2;
    u16* csr_src  = (u16*)ws; ws += (size_t)(T + 8) * 2;

    hipMemsetAsync(counts, 0, (size_t)M * 4, stream);
    int LB = (N + LROWS - 1) / LROWS;
    int CB = (T + 255) / 256;
    fused_pre<<<LB + CB, 256, 0, stream>>>(x, wl, bl, wr, br, gw, gb, xl, xr, gate4,
                                           e0, e1, e2, counts, rank, N, E, T, LB);
    int G = (M + 1023) / 1024;
    scan1<<<G, 1024, 0, stream>>>(counts, M, offsets, partials);
    scan2<<<1, 1024, 0, stream>>>(partials, G);
    scatter_all<<<(T + 255) / 256, 256, 0, stream>>>(e0, e1, e2, E, N, offsets, partials,
                                                     rank, csr_src, T);
    node_all<<<(int)(((size_t)N * 64 + 255) / 256), 256, 0, stream>>>(
        (const uint2*)xl, xr, csr_src, offsets, partials, att, cb, gate4, out, N, M, T);
}

// Round 6
// 350.254 us; speedup vs baseline: 1.0689x; 1.0689x over previous
//
#include <hip/hip_runtime.h>
#include <math.h>

typedef unsigned int uint32;
typedef unsigned short u16;

#if __has_builtin(__builtin_amdgcn_exp2f)
#define EXP2F(x) __builtin_amdgcn_exp2f(x)
#else
#define EXP2F(x) exp2f(x)
#endif

__device__ __forceinline__ u16 f2bf(float f) {  // RNE
    uint32 u = __float_as_uint(f);
    u += 0x7fffu + ((u >> 16) & 1u);
    return (u16)(u >> 16);
}
__device__ __forceinline__ float bflo(uint32 v) { return __uint_as_float(v << 16); }
__device__ __forceinline__ float bfhi(uint32 v) { return __uint_as_float(v & 0xffff0000u); }

// ---- fused: [0,LB) linear+gate blocks; [LB,..) count blocks ------------------
// List index layout: i = dst*3 + hop  (hop fastest -> waves for one node share a block)
#define LROWS 16
__global__ __launch_bounds__(256) void fused_pre(
    const float* __restrict__ x, const float* __restrict__ wl, const float* __restrict__ bl,
    const float* __restrict__ wr, const float* __restrict__ br,
    const float* __restrict__ gw, const float* __restrict__ gb,
    u16* __restrict__ xl, float* __restrict__ xr, float* __restrict__ gate4,
    const int* __restrict__ e0, const int* __restrict__ e1, const int* __restrict__ e2,
    int* __restrict__ counts, u16* __restrict__ rank,
    int N, int E, int T, int LB)
{
    if ((int)blockIdx.x >= LB) {
        int t = ((int)blockIdx.x - LB) * 256 + (int)threadIdx.x;
        if (t < T) {
            int hop, dst;
            if (t < E)          { hop = 0; dst = e0[E + t]; }
            else if (t < 2 * E) { hop = 1; dst = e1[t]; }
            else if (t < 3 * E) { hop = 2; dst = e2[t - E]; }
            else                { hop = 0; dst = t - 3 * E; }
            rank[t] = (u16)atomicAdd(counts + (size_t)dst * 3 + hop, 1);
        }
        return;
    }
    __shared__ float4 sx[LROWS][32];
    __shared__ float gbuf[LROWS][3];
    int t = threadIdx.x;
    int r0 = blockIdx.x * LROWS;
    int nr = min(LROWS, N - r0);
    {
        const float4* xi = (const float4*)(x + (size_t)r0 * 128);
        for (int i = t; i < nr * 32; i += 256) ((float4*)sx)[i] = xi[i];
    }
    __syncthreads();
    int mat = t >> 7, col = t & 127;
    const float* w = mat ? wr : wl;
    float acc[LROWS];
#pragma unroll
    for (int r = 0; r < LROWS; ++r) acc[r] = 0.f;
    for (int i = 0; i < 128; i += 4) {
        float w0 = w[(i + 0) * 128 + col];
        float w1 = w[(i + 1) * 128 + col];
        float w2 = w[(i + 2) * 128 + col];
        float w3 = w[(i + 3) * 128 + col];
#pragma unroll
        for (int r = 0; r < LROWS; ++r) {
            float4 xv = sx[r][i >> 2];
            acc[r] = fmaf(xv.x, w0, acc[r]);
            acc[r] = fmaf(xv.y, w1, acc[r]);
            acc[r] = fmaf(xv.z, w2, acc[r]);
            acc[r] = fmaf(xv.w, w3, acc[r]);
        }
    }
    if (mat) {
        float b = br[col];
        for (int r = 0; r < nr; ++r) xr[(size_t)(r0 + r) * 128 + col] = acc[r] + b;
    } else {
        float b = bl[col];
        for (int r = 0; r < nr; ++r) xl[(size_t)(r0 + r) * 128 + col] = f2bf(acc[r] + b);
    }
    if (t < nr * 3) {
        int r = t / 3, k = t - 3 * r;
        float s = 0.f;
        const float4* xrow = sx[r];
#pragma unroll 4
        for (int i = 0; i < 32; ++i) {
            float4 v = xrow[i];
            s += v.x * gw[(4 * i + 0) * 3 + k] + v.y * gw[(4 * i + 1) * 3 + k]
               + v.z * gw[(4 * i + 2) * 3 + k] + v.w * gw[(4 * i + 3) * 3 + k];
        }
        gbuf[r][k] = s + gb[k];
    }
    __syncthreads();
    if (t < nr) {
        float s0 = gbuf[t][0], s1 = gbuf[t][1], s2 = gbuf[t][2];
        float mx = fmaxf(s0, fmaxf(s1, s2));
        float e0v = __expf(s0 - mx), e1v = __expf(s1 - mx), e2v = __expf(s2 - mx);
        float inv = 1.f / (e0v + e1v + e2v);
        *(float4*)(gate4 + (size_t)(r0 + t) * 4) = make_float4(e0v * inv, e1v * inv, e2v * inv, 0.f);
    }
}

// ---- scans (block prefix folded at read time) --------------------------------
__global__ __launch_bounds__(1024) void scan1(const int* __restrict__ counts, int M,
                                              int* __restrict__ offsets, int* __restrict__ partials) {
    __shared__ int s[1024];
    int t = threadIdx.x;
    int i = blockIdx.x * 1024 + t;
    int v = (i < M) ? counts[i] : 0;
    s[t] = v;
    __syncthreads();
    for (int o = 1; o < 1024; o <<= 1) {
        int u = (t >= o) ? s[t - o] : 0;
        __syncthreads();
        s[t] += u;
        __syncthreads();
    }
    if (i < M) offsets[i] = s[t] - v;
    if (t == 1023) partials[blockIdx.x] = s[1023];
}

__global__ __launch_bounds__(1024) void scan2(int* __restrict__ partials, int G) {
    __shared__ int s[1024];
    int t = threadIdx.x;
    int v = (t < G) ? partials[t] : 0;
    s[t] = v;
    __syncthreads();
    for (int o = 1; o < 1024; o <<= 1) {
        int u = (t >= o) ? s[t - o] : 0;
        __syncthreads();
        s[t] += u;
        __syncthreads();
    }
    if (t < G) partials[t] = s[t] - v;
}

__global__ void scatter_all(const int* __restrict__ e0, const int* __restrict__ e1,
                            const int* __restrict__ e2, int E, int N,
                            const int* __restrict__ offsets, const int* __restrict__ partials,
                            const u16* __restrict__ rank, u16* __restrict__ csr_src, int T) {
    int t = blockIdx.x * blockDim.x + threadIdx.x;
    if (t >= T) return;
    int hop, src, dst;
    if (t < E)          { hop = 0; src = e0[t];         dst = e0[E + t]; }
    else if (t < 2 * E) { hop = 1; src = e1[t - E];     dst = e1[t]; }
    else if (t < 3 * E) { hop = 2; src = e2[t - 2 * E]; dst = e2[t - E]; }
    else                { hop = 0; src = t - 3 * E;     dst = src; }
    int i = dst * 3 + hop;
    int p = offsets[i] + partials[i >> 10] + (int)rank[t];
    csr_src[p] = (u16)src;
}

// ---- node kernel: one wave per (node,hop) list; 2 edges/iter, 32 lanes/edge --
// half = lane>>5 (edge slot), l5 = lane&31 covers features 4*l5..+3; head = l5>>3.
__global__ __launch_bounds__(256) void node_hop(
    const uint2* __restrict__ xlv,   // [N*32], uint2 = 4 bf16
    const float* __restrict__ xr,    // [N*128]
    const u16* __restrict__ csr,
    const int* __restrict__ offsets, const int* __restrict__ partials,
    const float* __restrict__ att,   // [3*128]
    const float* __restrict__ bias,  // [3*32]
    float* __restrict__ msgs,        // [3N*32]
    int N, int M, int T)
{
    const float L2E = 1.44269504088896f;
    int i = (int)((blockIdx.x * (size_t)blockDim.x + threadIdx.x) >> 6);  // list id = 3n+h
    int lane = threadIdx.x & 63;
    if (i >= M) return;
    int n = (int)((uint32)i / 3u);
    int h = i - 3 * n;
    int half = lane >> 5, l5 = lane & 31;

    float4 r4 = ((const float4*)(xr + (size_t)n * 128))[l5];
    float4 a4 = ((const float4*)(att + h * 128))[l5];
    a4.x *= L2E; a4.y *= L2E; a4.z *= L2E; a4.w *= L2E;
    int beg = offsets[i] + partials[i >> 10];
    int i1 = i + 1;
    int end = (i1 == M) ? T : (offsets[i1] + partials[i1 >> 10]);

    float d = 0.f, acc0 = 0.f, acc1 = 0.f, acc2 = 0.f, acc3 = 0.f;
    if (beg < end) {
        int s0 = csr[min(beg + half, end - 1)];
        uint2 lv = xlv[(size_t)s0 * 32 + l5];
        for (int e = beg; e < end; e += 2) {
            uint2 cv = lv;
            bool valid = (e + half) < end;
            if (e + 2 < end) {
                int ns = csr[min(e + 2 + half, end - 1)];
                lv = xlv[(size_t)ns * 32 + l5];
            }
            float lx0 = bflo(cv.x), lx1 = bfhi(cv.x);
            float lx2 = bflo(cv.y), lx3 = bfhi(cv.y);
            float g0 = lx0 + r4.x, g1 = lx1 + r4.y;
            float g2 = lx2 + r4.z, g3 = lx3 + r4.w;
            float p;                                // leaky = 0.6g + 0.4|g| (exact)
            p = fmaf(0.4f, fabsf(g0), 0.6f * g0) * a4.x;
            p = fmaf(fmaf(0.4f, fabsf(g1), 0.6f * g1), a4.y, p);
            p = fmaf(fmaf(0.4f, fabsf(g2), 0.6f * g2), a4.z, p);
            p = fmaf(fmaf(0.4f, fabsf(g3), 0.6f * g3), a4.w, p);
            p += __shfl_xor(p, 1);
            p += __shfl_xor(p, 2);
            p += __shfl_xor(p, 4);                  // head logit * log2e
            float wv = EXP2F(p);
            wv = valid ? wv : 0.f;
            d += wv;
            acc0 = fmaf(wv, lx0, acc0);
            acc1 = fmaf(wv, lx1, acc1);
            acc2 = fmaf(wv, lx2, acc2);
            acc3 = fmaf(wv, lx3, acc3);
        }
    }
    // combine edge halves (lane bit 5)
    d += __shfl_xor(d, 32);
    acc0 += __shfl_xor(acc0, 32);
    acc1 += __shfl_xor(acc1, 32);
    acc2 += __shfl_xor(acc2, 32);
    acc3 += __shfl_xor(acc3, 32);
    float inv = (d > 0.f) ? (1.0f / d) : 0.f;  // deg==0 -> msg = bias
    float q0 = acc0 * inv, q1 = acc1 * inv, q2 = acc2 * inv, q3 = acc3 * inv;
    // sum over 4 heads (lane bits 3,4)
    q0 += __shfl_xor(q0, 8);  q0 += __shfl_xor(q0, 16);
    q1 += __shfl_xor(q1, 8);  q1 += __shfl_xor(q1, 16);
    q2 += __shfl_xor(q2, 8);  q2 += __shfl_xor(q2, 16);
    q3 += __shfl_xor(q3, 8);  q3 += __shfl_xor(q3, 16);
    if (lane < 8) {
        float4 b4 = ((const float4*)(bias + h * 32))[lane];
        ((float4*)(msgs + (size_t)i * 32))[lane] =
            make_float4(fmaf(q0, 0.25f, b4.x), fmaf(q1, 0.25f, b4.y),
                        fmaf(q2, 0.25f, b4.z), fmaf(q3, 0.25f, b4.w));
    }
}

// ---- combine: out[n] = sum_h gate[n][h] * msgs[3n+h] -------------------------
__global__ __launch_bounds__(256) void combine(
    const float* __restrict__ msgs, const float* __restrict__ gate4,
    float* __restrict__ out, int N)
{
    int tid = blockIdx.x * 256 + threadIdx.x;  // N*8 threads, one float4 each
    if (tid >= N * 8) return;
    int n = tid >> 3, j = tid & 7;
    float4 g = ((const float4*)gate4)[n];
    float4 m0 = ((const float4*)(msgs + (size_t)(3 * n + 0) * 32))[j];
    float4 m1 = ((const float4*)(msgs + (size_t)(3 * n + 1) * 32))[j];
    float4 m2 = ((const float4*)(msgs + (size_t)(3 * n + 2) * 32))[j];
    float4 o;
    o.x = g.x * m0.x + g.y * m1.x + g.z * m2.x;
    o.y = g.x * m0.y + g.y * m1.y + g.z * m2.y;
    o.z = g.x * m0.z + g.y * m1.z + g.z * m2.z;
    o.w = g.x * m0.w + g.y * m1.w + g.z * m2.w;
    ((float4*)out)[tid] = o;
}

// ---------------- launch ----------------
extern "C" void kernel_launch(void* const* d_in, const int* in_sizes, int n_in,
                              void* d_out, int out_size, void* d_ws, size_t ws_size,
                              hipStream_t stream) {
    const float* x  = (const float*)d_in[0];
    const int* e0 = (const int*)d_in[1];
    const int* e1 = (const int*)d_in[2];
    const int* e2 = (const int*)d_in[3];
    const float* wl = (const float*)d_in[4];
    const float* bl = (const float*)d_in[5];
    const float* wr = (const float*)d_in[6];
    const float* br = (const float*)d_in[7];
    const float* att = (const float*)d_in[8];
    const float* cb  = (const float*)d_in[9];
    const float* gw  = (const float*)d_in[10];
    const float* gb  = (const float*)d_in[11];

    int N = in_sizes[0] / 128;
    int E = in_sizes[1] / 2;
    float* out = (float*)d_out;

    char* ws = (char*)d_ws;
    u16* xl      = (u16*)ws;   ws += (size_t)N * 128 * 2;
    float* xr    = (float*)ws; ws += (size_t)N * 128 * 4;
    float* gate4 = (float*)ws; ws += (size_t)N * 4 * 4;
    int M = 3 * N;
    int T = 3 * E + N;
    int* offsets  = (int*)ws; ws += (size_t)M * 4;
    int* counts   = (int*)ws; ws += (size_t)M * 4;
    int* partials = (int*)ws; ws += 4096;
    u16* rank     = (u16*)ws; ws += (size_t)T * 2;
    u16* csr_src  = (u16*)ws; ws += (size_t)(T + 8) * 2;
    float* msgs   = (float*)(((uintptr_t)ws + 15) & ~(uintptr_t)15);

    hipMemsetAsync(counts, 0, (size_t)M * 4, stream);
    int LB = (N + LROWS - 1) / LROWS;
    int CB = (T + 255) / 256;
    fused_pre<<<LB + CB, 256, 0, stream>>>(x, wl, bl, wr, br, gw, gb, xl, xr, gate4,
                                           e0, e1, e2, counts, rank, N, E, T, LB);
    int G = (M + 1023) / 1024;
    scan1<<<G, 1024, 0, stream>>>(counts, M, offsets, partials);
    scan2<<<1, 1024, 0, stream>>>(partials, G);
    scatter_all<<<(T + 255) / 256, 256, 0, stream>>>(e0, e1, e2, E, N, offsets, partials,
                                                     rank, csr_src, T);
    node_hop<<<(int)(((size_t)M * 64 + 255) / 256), 256, 0, stream>>>(
        (const uint2*)xl, xr, csr_src, offsets, partials, att, cb, msgs, N, M, T);
    combine<<<(N * 8 + 255) / 256, 256, 0, stream>>>(msgs, gate4, out, N);
}